// Round 3
// baseline (463.245 us; speedup 1.0000x reference)
//
#include <hip/hip_runtime.h>

typedef __attribute__((ext_vector_type(8))) short short8;   // 8 bf16 (MFMA A/B frag)
typedef __attribute__((ext_vector_type(4))) float f32x4;    // MFMA C/D frag

#define NB 4            // batches per block

__device__ __forceinline__ float bf2f(unsigned short u) {
    unsigned int x = ((unsigned int)u) << 16;
    return __builtin_bit_cast(float, x);
}
__device__ __forceinline__ unsigned short f2bf(float f) {
    unsigned int x = __builtin_bit_cast(unsigned int, f);
    x = (x + 0x7fff + ((x >> 16) & 1)) >> 16;   // round-to-nearest-even
    return (unsigned short)x;
}

// ws layout: [0,8192) bf16 B-fragments; [8192,8704) fp32 a[128]; [8704,8708) int flag_h
//
// Dtype sniffer (insurance): fp32 viewed as u16 has low-halves = mantissa junk;
// ~48% of those decode to |bf16| >= 64. Genuine data here is < 8 in magnitude.
__global__ void prep_kernel(const unsigned short* __restrict__ hraw,
                            const unsigned short* __restrict__ Wraw,
                            const unsigned short* __restrict__ araw,
                            unsigned short* __restrict__ bfrag,
                            float* __restrict__ a_f32,
                            int* __restrict__ flags) {
    const int lane = threadIdx.x;   // 64 threads
    const int c = lane & 15, q = lane >> 4;

    auto sniff = [&](const unsigned short* p) -> int {
        int bad = 0;
        for (int i = lane; i < 128; i += 64) {
            unsigned e = (p[i] >> 7) & 0xFF;
            if (e >= 0x85) bad = 1;          // |bf16| >= 64 -> must be fp32 junk
        }
        return (__ballot(bad) != 0ULL) ? 1 : 0;
    };
    const int fh = sniff(hraw);
    const int fw = sniff(Wraw);
    const int fa = sniff(araw);
    if (lane == 0) flags[0] = fh;

    // a -> fp32 copy
    const float* af = (const float*)araw;
    for (int i = lane; i < 128; i += 64)
        a_f32[i] = fa ? af[i] : bf2f(araw[i]);

    // W (64x64 row-major k x n) -> MFMA B-fragment layout (bf16):
    // lane holds B[k = half*32 + q*8 + j][n = t*16 + c] at flat ((t*2+half)*64+lane)*8+j
    const float* Wf = (const float*)Wraw;
    for (int t = 0; t < 4; ++t)
        for (int half = 0; half < 2; ++half)
            for (int j = 0; j < 8; ++j) {
                const int n = t * 16 + c;
                const int k = half * 32 + q * 8 + j;
                const unsigned short w = fw ? f2bf(Wf[k * 64 + n]) : Wraw[k * 64 + n];
                bfrag[((t * 2 + half) * 64 + lane) * 8 + j] = w;
            }
}

// Drain-free workgroup barrier: only LDS ordering is needed (sc).
// Global prefetch loads stay in flight across it (no vmcnt(0) drain like
// __syncthreads emits). sched_barrier(0) blocks the compiler from hoisting
// LDS-result consumers above the barrier (rule #18 miscompile).
__device__ __forceinline__ void lds_barrier() {
    asm volatile("s_waitcnt lgkmcnt(0)" ::: "memory");
    __builtin_amdgcn_s_barrier();
    __builtin_amdgcn_sched_barrier(0);
}

// One block per NB consecutive batches. 4 waves; wave w computes Wh rows [16w,16w+16).
// Wh never leaves registers: stores go straight from the MFMA C/D layout
// (lane q,c holds Wh[16w+4q+r][16t+c]) -> 16 scalar stores/lane, each store
// instruction covering 4 full 64B lines. Only the 64 scores cross waves (sc),
// double-buffered so ONE barrier per batch suffices.
__global__ __launch_bounds__(256, 4) void gat_kernel(
    const unsigned short* __restrict__ h,     // (B,64,64) fp32 (or bf16; see flag)
    const unsigned short* __restrict__ bfrag, // prepped W frags (bf16, ws)
    const float* __restrict__ a_f32,          // a as fp32 (ws)
    const int* __restrict__ flags,
    float* __restrict__ out)                  // (B,64,64) fp32
{
    __shared__ float sc[2][64];   // sc[i&1][0] = robot@a1 ; [r>=1] = Wh[r]@a2

    const int tid  = threadIdx.x;
    const int w    = tid >> 6;
    const int lane = tid & 63;
    const int c    = lane & 15;   // MFMA col / A-row selector
    const int q    = lane >> 4;   // quad
    const int fh   = flags[0];    // wave-uniform
    const int b0   = blockIdx.x * NB;

    // ---- batch-invariant state, hoisted once per block ----
    short8 bfr[8];                 // B-fragments: 8 x 16B = 32 VGPR
#pragma unroll
    for (int i = 0; i < 8; ++i)
        bfr[i] = *(const short8*)(bfrag + (i * 64 + lane) * 8);

    float a1f[4], a2f[4];
#pragma unroll
    for (int t = 0; t < 4; ++t) {
        a1f[t] = a_f32[t * 16 + c];
        a2f[t] = a_f32[64 + t * 16 + c];
    }

    const int rowsel = w * 16 + c;            // A-frag row this lane loads

    // Prefetch registers. bf16 path reuses px0/px1 via bit_cast (16B each).
    float4 px0, px1, px2, px3;
    px2 = make_float4(0.f, 0.f, 0.f, 0.f);
    px3 = px2;

    auto issue_load = [&](int b) {
        const size_t off = (size_t)b * 4096 + (size_t)rowsel * 64;
        if (fh) {       // fp32 h: 4 x float4
            const float* hf = (const float*)h + off;
            px0 = *(const float4*)(hf + q * 8);
            px1 = *(const float4*)(hf + q * 8 + 4);
            px2 = *(const float4*)(hf + 32 + q * 8);
            px3 = *(const float4*)(hf + 32 + q * 8 + 4);
        } else {        // bf16 h: 2 x 16B
            const unsigned short* hb = h + off;
            px0 = *(const float4*)(hb + q * 8);
            px1 = *(const float4*)(hb + 32 + q * 8);
        }
    };

    issue_load(b0);

    for (int i = 0; i < NB; ++i) {
        const int b = b0 + i;
        float* const scb = sc[i & 1];

        // ---- build A fragments from prefetched registers ----
        short8 af0, af1;
        if (fh) {
            af0 = short8{(short)f2bf(px0.x), (short)f2bf(px0.y), (short)f2bf(px0.z), (short)f2bf(px0.w),
                         (short)f2bf(px1.x), (short)f2bf(px1.y), (short)f2bf(px1.z), (short)f2bf(px1.w)};
            af1 = short8{(short)f2bf(px2.x), (short)f2bf(px2.y), (short)f2bf(px2.z), (short)f2bf(px2.w),
                         (short)f2bf(px3.x), (short)f2bf(px3.y), (short)f2bf(px3.z), (short)f2bf(px3.w)};
        } else {
            af0 = __builtin_bit_cast(short8, px0);
            af1 = __builtin_bit_cast(short8, px1);
        }

        // ---- prefetch next batch ASAP: hides HBM latency under MFMA+softmax+stores ----
        if (i + 1 < NB) issue_load(b + 1);

        // ---- Wh = h @ W : 4 col-tiles x (K=64 as 2 mfma) ----
        f32x4 acc[4];
#pragma unroll
        for (int t = 0; t < 4; ++t) {
            f32x4 z = {0.f, 0.f, 0.f, 0.f};
            z = __builtin_amdgcn_mfma_f32_16x16x32_bf16(af0, bfr[2 * t + 0], z, 0, 0, 0);
            z = __builtin_amdgcn_mfma_f32_16x16x32_bf16(af1, bfr[2 * t + 1], z, 0, 0, 0);
            acc[t] = z;
        }

        // ---- score dots -> sc (double-buffered) ----
        // C/D layout (verified m89): col = lane&15, row(in tile) = q*4 + r
#pragma unroll
        for (int r = 0; r < 4; ++r) {
            const int row = w * 16 + q * 4 + r;
            float d2 = 0.f;
#pragma unroll
            for (int t = 0; t < 4; ++t) d2 += acc[t][r] * a2f[t];
#pragma unroll
            for (int m = 1; m < 16; m <<= 1) d2 += __shfl_xor(d2, m, 64);
            if (row == 0) {                    // uniform over the 16-lane c-group
                float d1 = 0.f;
#pragma unroll
                for (int t = 0; t < 4; ++t) d1 += acc[t][r] * a1f[t];
#pragma unroll
                for (int m = 1; m < 16; m <<= 1) d1 += __shfl_xor(d1, m, 64);
                d2 = d1;                       // row 0 carries robot@a1
            }
            if (c == 0) scb[row] = d2;
        }

        lds_barrier();   // sc visible to all waves; h prefetch still in flight

        // ---- softmax over rows 1..63 of (sc[r] + sc[0]); every wave, in-register ----
        const float srob = scb[0];
        float v = (lane >= 1) ? scb[lane] + srob : -1e30f;
        float mx = v;
#pragma unroll
        for (int s = 1; s < 64; s <<= 1) mx = fmaxf(mx, __shfl_xor(mx, s, 64));
        float e = (lane >= 1) ? __expf(v - mx) : 0.f;
        float ssum = e;
#pragma unroll
        for (int s = 1; s < 64; s <<= 1) ssum += __shfl_xor(ssum, s, 64);
        const float preg = (lane == 0) ? 1.0f : e / ssum;   // p for row = lane

        // ---- epilogue: scale + ELU straight from acc registers ----
        // store (t,r): 64 lanes cover rows {16w+4q+r} x cols [16t,16t+16) -> 4 full
        // 64B lines per instruction, rows 1KB apart. No LDS round-trip.
        float* ob = out + (size_t)b * 4096;
#pragma unroll
        for (int r = 0; r < 4; ++r) {
            const int row = w * 16 + q * 4 + r;
            const float p = __shfl(preg, row, 64);
            float* orow = ob + (size_t)row * 64 + c;
#pragma unroll
            for (int t = 0; t < 4; ++t) {
                float x = p * acc[t][r];
                x = (x > 0.f) ? x : (__expf(x) - 1.0f);   // elu, alpha=1
                orow[t * 16] = x;
            }
        }
        // no second barrier: sc is double-buffered; a wave can only reach its
        // next write of sc[i&1] after passing barrier i+1, which every other
        // wave reaches only after its reads of sc[i&1] completed.
    }
}

extern "C" void kernel_launch(void* const* d_in, const int* in_sizes, int n_in,
                              void* d_out, int out_size, void* d_ws, size_t ws_size,
                              hipStream_t stream) {
    const unsigned short* h = (const unsigned short*)d_in[0];
    const unsigned short* W = (const unsigned short*)d_in[1];
    const unsigned short* a = (const unsigned short*)d_in[2];
    float*          out   = (float*)d_out;
    unsigned short* bfrag = (unsigned short*)d_ws;                    // 8 KB
    float*          a_f32 = (float*)((char*)d_ws + 8192);            // 512 B
    int*            flags = (int*)((char*)d_ws + 8704);

    prep_kernel<<<1, 64, 0, stream>>>(h, W, a, bfrag, a_f32, flags); // ws re-poisoned -> redo

    const int B = in_sizes[0] / 4096;                                // 16384
    gat_kernel<<<B / NB, 256, 0, stream>>>(h, bfrag, a_f32, flags, out);
}

// Round 4
// 459.871 us; speedup vs baseline: 1.0073x; 1.0073x over previous
//
#include <hip/hip_runtime.h>

typedef __attribute__((ext_vector_type(8))) short short8;   // 8 bf16 (MFMA A/B frag)
typedef __attribute__((ext_vector_type(4))) float f32x4;    // MFMA C/D frag

__device__ __forceinline__ float bf2f(unsigned short u) {
    unsigned int x = ((unsigned int)u) << 16;
    return __builtin_bit_cast(float, x);
}
__device__ __forceinline__ unsigned short f2bf(float f) {
    unsigned int x = __builtin_bit_cast(unsigned int, f);
    x = (x + 0x7fff + ((x >> 16) & 1)) >> 16;   // round-to-nearest-even
    return (unsigned short)x;
}

// ws layout: [0,8192) bf16 B-fragments; [8192,8704) fp32 a[128]; [8704,8708) int flag_h
//
// Dtype sniffer (insurance): fp32 viewed as u16 has low-halves = mantissa junk;
// ~48% of those decode to |bf16| >= 64. Genuine data here is < 8 in magnitude.
__global__ void prep_kernel(const unsigned short* __restrict__ hraw,
                            const unsigned short* __restrict__ Wraw,
                            const unsigned short* __restrict__ araw,
                            unsigned short* __restrict__ bfrag,
                            float* __restrict__ a_f32,
                            int* __restrict__ flags) {
    const int lane = threadIdx.x;   // 64 threads
    const int c = lane & 15, q = lane >> 4;

    auto sniff = [&](const unsigned short* p) -> int {
        int bad = 0;
        for (int i = lane; i < 128; i += 64) {
            unsigned e = (p[i] >> 7) & 0xFF;
            if (e >= 0x85) bad = 1;          // |bf16| >= 64 -> must be fp32 junk
        }
        return (__ballot(bad) != 0ULL) ? 1 : 0;
    };
    const int fh = sniff(hraw);
    const int fw = sniff(Wraw);
    const int fa = sniff(araw);
    if (lane == 0) flags[0] = fh;

    // a -> fp32 copy
    const float* af = (const float*)araw;
    for (int i = lane; i < 128; i += 64)
        a_f32[i] = fa ? af[i] : bf2f(araw[i]);

    // W (64x64 row-major k x n) -> MFMA B-fragment layout (bf16):
    // lane holds B[k = half*32 + q*8 + j][n = t*16 + c] at flat ((t*2+half)*64+lane)*8+j
    const float* Wf = (const float*)Wraw;
    for (int t = 0; t < 4; ++t)
        for (int half = 0; half < 2; ++half)
            for (int j = 0; j < 8; ++j) {
                const int n = t * 16 + c;
                const int k = half * 32 + q * 8 + j;
                const unsigned short w = fw ? f2bf(Wf[k * 64 + n]) : Wraw[k * 64 + n];
                bfrag[((t * 2 + half) * 64 + lane) * 8 + j] = w;
            }
}

// Drain-free workgroup barrier: only LDS ordering is needed (sc, 256 B).
// No vmcnt(0) drain like __syncthreads emits; sched_barrier(0) blocks the
// compiler from hoisting LDS-result consumers above it (rule #18 miscompile).
__device__ __forceinline__ void lds_barrier() {
    asm volatile("s_waitcnt lgkmcnt(0)" ::: "memory");
    __builtin_amdgcn_s_barrier();
    __builtin_amdgcn_sched_barrier(0);
}

// One block per batch element; 4 waves; wave w owns Wh rows [16w,16w+16).
// Shortest-critical-path structure: h loads issue at cycle 0, Wh never leaves
// registers (stores go straight from the MFMA C/D layout: lane (q,c) holds
// Wh[16w+4q+r][16t+c]; one scalar store covers 4 full 64B lines), only the 64
// scores cross waves -> single light barrier, then the block retires.
// Latency is hidden by block churn (16384 independent blocks), not intra-block
// pipelining — rounds 2/3 showed the NB-loop variant is no better.
__global__ __launch_bounds__(256, 4) void gat_kernel(
    const unsigned short* __restrict__ h,     // (B,64,64) fp32 (or bf16; see flag)
    const unsigned short* __restrict__ bfrag, // prepped W frags (bf16, ws)
    const float* __restrict__ a_f32,          // a as fp32 (ws)
    const int* __restrict__ flags,
    float* __restrict__ out)                  // (B,64,64) fp32
{
    __shared__ float sc[64];      // sc[0] = robot@a1 ; sc[r>=1] = Wh[r]@a2

    const int tid  = threadIdx.x;
    const int w    = tid >> 6;
    const int lane = tid & 63;
    const int c    = lane & 15;   // MFMA col / A-row selector
    const int q    = lane >> 4;   // quad
    const int b    = blockIdx.x;
    const int fh   = flags[0];    // wave-uniform (L2-hot scalar load)

    // ---- h loads first: longest latency (HBM), issue at block start ----
    const int rowsel = w * 16 + c;            // A-frag row this lane loads
    const size_t off = (size_t)b * 4096 + (size_t)rowsel * 64;
    float4 px0, px1, px2, px3;
    px2 = make_float4(0.f, 0.f, 0.f, 0.f);
    px3 = px2;
    if (fh) {       // fp32 h: 4 x float4
        const float* hf = (const float*)h + off;
        px0 = *(const float4*)(hf + q * 8);
        px1 = *(const float4*)(hf + q * 8 + 4);
        px2 = *(const float4*)(hf + 32 + q * 8);
        px3 = *(const float4*)(hf + 32 + q * 8 + 4);
    } else {        // bf16 h: 2 x 16B
        const unsigned short* hb = h + off;
        px0 = *(const float4*)(hb + q * 8);
        px1 = *(const float4*)(hb + 32 + q * 8);
    }

    // ---- batch-invariant operands (L2-hot after first blocks) ----
    short8 bfr[8];                 // B-fragments: 8 x 16B = 32 VGPR
#pragma unroll
    for (int i = 0; i < 8; ++i)
        bfr[i] = *(const short8*)(bfrag + (i * 64 + lane) * 8);

    float a1f[4], a2f[4];
#pragma unroll
    for (int t = 0; t < 4; ++t) {
        a1f[t] = a_f32[t * 16 + c];
        a2f[t] = a_f32[64 + t * 16 + c];
    }

    // ---- build A fragments ----
    short8 af0, af1;
    if (fh) {
        af0 = short8{(short)f2bf(px0.x), (short)f2bf(px0.y), (short)f2bf(px0.z), (short)f2bf(px0.w),
                     (short)f2bf(px1.x), (short)f2bf(px1.y), (short)f2bf(px1.z), (short)f2bf(px1.w)};
        af1 = short8{(short)f2bf(px2.x), (short)f2bf(px2.y), (short)f2bf(px2.z), (short)f2bf(px2.w),
                     (short)f2bf(px3.x), (short)f2bf(px3.y), (short)f2bf(px3.z), (short)f2bf(px3.w)};
    } else {
        af0 = __builtin_bit_cast(short8, px0);
        af1 = __builtin_bit_cast(short8, px1);
    }

    // ---- Wh = h @ W : 4 col-tiles x (K=64 as 2 mfma) ----
    f32x4 acc[4];
#pragma unroll
    for (int t = 0; t < 4; ++t) {
        f32x4 z = {0.f, 0.f, 0.f, 0.f};
        z = __builtin_amdgcn_mfma_f32_16x16x32_bf16(af0, bfr[2 * t + 0], z, 0, 0, 0);
        z = __builtin_amdgcn_mfma_f32_16x16x32_bf16(af1, bfr[2 * t + 1], z, 0, 0, 0);
        acc[t] = z;
    }

    // ---- score dots -> sc ----
    // C/D layout (verified m89): col = lane&15, row(in tile) = q*4 + r
#pragma unroll
    for (int r = 0; r < 4; ++r) {
        const int row = w * 16 + q * 4 + r;
        float d2 = 0.f;
#pragma unroll
        for (int t = 0; t < 4; ++t) d2 += acc[t][r] * a2f[t];
#pragma unroll
        for (int m = 1; m < 16; m <<= 1) d2 += __shfl_xor(d2, m, 64);
        if (row == 0) {                    // uniform over the 16-lane c-group
            float d1 = 0.f;
#pragma unroll
            for (int t = 0; t < 4; ++t) d1 += acc[t][r] * a1f[t];
#pragma unroll
            for (int m = 1; m < 16; m <<= 1) d1 += __shfl_xor(d1, m, 64);
            d2 = d1;                       // row 0 carries robot@a1
        }
        if (c == 0) sc[row] = d2;
    }

    lds_barrier();   // sc visible to all waves

    // ---- softmax over rows 1..63 of (sc[r] + sc[0]); every wave, in-register ----
    const float srob = sc[0];
    float v = (lane >= 1) ? sc[lane] + srob : -1e30f;
    float mx = v;
#pragma unroll
    for (int s = 1; s < 64; s <<= 1) mx = fmaxf(mx, __shfl_xor(mx, s, 64));
    float e = (lane >= 1) ? __expf(v - mx) : 0.f;
    float ssum = e;
#pragma unroll
    for (int s = 1; s < 64; s <<= 1) ssum += __shfl_xor(ssum, s, 64);
    const float preg = (lane == 0) ? 1.0f : e / ssum;   // p for row = lane

    // ---- epilogue: scale + ELU straight from acc registers ----
    // store (t,r): 64 lanes cover rows {16w+4q+r} x cols [16t,16t+16) -> 4 full
    // 64B lines per instruction, rows 1KB apart. No LDS round-trip.
    float* ob = out + (size_t)b * 4096;
#pragma unroll
    for (int r = 0; r < 4; ++r) {
        const int row = w * 16 + q * 4 + r;
        const float p = __shfl(preg, row, 64);
        float* orow = ob + (size_t)row * 64 + c;
#pragma unroll
        for (int t = 0; t < 4; ++t) {
            float x = p * acc[t][r];
            x = (x > 0.f) ? x : (__expf(x) - 1.0f);   // elu, alpha=1
            orow[t * 16] = x;
        }
    }
}

extern "C" void kernel_launch(void* const* d_in, const int* in_sizes, int n_in,
                              void* d_out, int out_size, void* d_ws, size_t ws_size,
                              hipStream_t stream) {
    const unsigned short* h = (const unsigned short*)d_in[0];
    const unsigned short* W = (const unsigned short*)d_in[1];
    const unsigned short* a = (const unsigned short*)d_in[2];
    float*          out   = (float*)d_out;
    unsigned short* bfrag = (unsigned short*)d_ws;                    // 8 KB
    float*          a_f32 = (float*)((char*)d_ws + 8192);            // 512 B
    int*            flags = (int*)((char*)d_ws + 8704);

    prep_kernel<<<1, 64, 0, stream>>>(h, W, a, bfrag, a_f32, flags); // ws re-poisoned -> redo

    const int B = in_sizes[0] / 4096;                                // 16384
    gat_kernel<<<B, 256, 0, stream>>>(h, bfrag, a_f32, flags, out);
}